// Round 8
// baseline (217.740 us; speedup 1.0000x reference)
//
#include <hip/hip_runtime.h>

typedef unsigned short u16;
typedef unsigned int   u32;
typedef __attribute__((ext_vector_type(8))) short bf16x8;
typedef __attribute__((ext_vector_type(4))) float f32x4;

#define BB   8
#define CIN  256
#define NT   256
#define EMB  512
#define NH   8

// ---- bf16 <-> f32 via raw bits ----
__device__ __forceinline__ float bf2f(u16 b) {
    union { u32 u; float f; } v; v.u = ((u32)b) << 16; return v.f;
}
__device__ __forceinline__ u16 f2bf(float f) {
    union { float f; u32 u; } v; v.f = f;
    u32 r = v.u + 0x7FFFu + ((v.u >> 16) & 1u);  // RNE
    return (u16)(r >> 16);
}
__device__ __forceinline__ float ld(const u16* base, size_t idx, int f32) {
    return f32 ? ((const float*)base)[idx] : bf2f(base[idx]);
}

struct alignas(16) U32x4 { u32 x, y, z, w; };
struct alignas(8)  U32x2 { u32 x, y; };

// ---------------- K0b: transpose X + split-bf16 convert X and W ----------------
__global__ void k_xpose(
    const u16* __restrict__ x1, const u16* __restrict__ x2,
    const u16* __restrict__ Wq, const u16* __restrict__ Wk, const u16* __restrict__ Wv,
    u16* __restrict__ XTh, u16* __restrict__ XTl,
    u16* __restrict__ WCh, u16* __restrict__ WCl,
    int* __restrict__ flag)
{
    __shared__ int cnt;
    __shared__ float T[64][65];
    int t = threadIdx.x;
    if (t == 0) cnt = 0;
    __syncthreads();
    {
        int local = 0;
        for (int j = t * 16; j < t * 16 + 16; j += 2) {
            u16 w = x1[j];
            int e = (w >> 7) & 0xFF;
            if (e >= 100 && e <= 145) local++;
        }
        atomicAdd(&cnt, local);
    }
    __syncthreads();
    const int f32 = (cnt >= 1200) ? 0 : 1;

    int bid = blockIdx.x;
    if (bid == 0 && t == 0) *flag = f32;

    if (bid < 256) {
        // X transpose: one 64x64 subtile per block
        int inp = bid >> 7, b = (bid >> 4) & 7, ks = (bid >> 2) & 3, ns = bid & 3;
        const u16* X = inp ? x2 : x1;
#pragma unroll
        for (int p = 0; p < 4; ++p) {
            int kk = p * 16 + (t >> 4);
            int nn = (t & 15) * 4;
#pragma unroll
            for (int j = 0; j < 4; ++j)
                T[kk][nn + j] = ld(X, ((size_t)b * CIN + ks * 64 + kk) * NT + ns * 64 + nn + j, f32);
        }
        __syncthreads();
#pragma unroll
        for (int it = 0; it < 2; ++it) {
            int g = it * 256 + t;
            int nn = g >> 3, kg = g & 7;
            u32 hw[4], lw[4];
#pragma unroll
            for (int e = 0; e < 4; ++e) {
                float va = T[kg * 8 + 2 * e][nn];
                float vb = T[kg * 8 + 2 * e + 1][nn];
                u16 ha = f2bf(va), hb = f2bf(vb);
                u16 la = f2bf(va - bf2f(ha)), lb = f2bf(vb - bf2f(hb));
                hw[e] = (u32)ha | ((u32)hb << 16);
                lw[e] = (u32)la | ((u32)lb << 16);
            }
            size_t dst = (((size_t)(inp * 8 + b) * 256) + ns * 64 + nn) * 256 + ks * 64 + kg * 8;
            U32x4 H; H.x = hw[0]; H.y = hw[1]; H.z = hw[2]; H.w = hw[3];
            U32x4 L; L.x = lw[0]; L.y = lw[1]; L.z = lw[2]; L.w = lw[3];
            *(U32x4*)&XTh[dst] = H;
            *(U32x4*)&XTl[dst] = L;
        }
    } else {
        // W convert: 128 rows per block
        int wb = bid - 256;                 // 0..11
        int proj = wb >> 2, qtr = wb & 3;
        const u16* W = (proj == 0) ? Wq : (proj == 1) ? Wk : Wv;
#pragma unroll
        for (int it = 0; it < 16; ++it) {
            int g = it * 256 + t;
            int row = g >> 5, kg = g & 31;
            int o = qtr * 128 + row;
            u32 hw[4], lw[4];
#pragma unroll
            for (int e = 0; e < 4; ++e) {
                float va = ld(W, (size_t)o * CIN + kg * 8 + 2 * e, f32);
                float vb = ld(W, (size_t)o * CIN + kg * 8 + 2 * e + 1, f32);
                u16 ha = f2bf(va), hb = f2bf(vb);
                u16 la = f2bf(va - bf2f(ha)), lb = f2bf(vb - bf2f(hb));
                hw[e] = (u32)ha | ((u32)hb << 16);
                lw[e] = (u32)la | ((u32)lb << 16);
            }
            size_t dst = ((size_t)(proj * 512 + o)) * 256 + kg * 8;
            U32x4 H; H.x = hw[0]; H.y = hw[1]; H.z = hw[2]; H.w = hw[3];
            U32x4 L; L.x = lw[0]; L.y = lw[1]; L.z = lw[2]; L.w = lw[3];
            *(U32x4*)&WCh[dst] = H;
            *(U32x4*)&WCl[dst] = L;
        }
    }
}

// ---------------- K1: QKV projections, MFMA 16x16x32 bf16 (split-precision) ----
__global__ __launch_bounds__(256) void k_qkv(
    const u16* __restrict__ XTh, const u16* __restrict__ XTl,
    const u16* __restrict__ WCh, const u16* __restrict__ WCl,
    const u16* __restrict__ bq, const u16* __restrict__ bk, const u16* __restrict__ bv,
    u16* __restrict__ Qg, u16* __restrict__ Kg, u16* __restrict__ Vg,
    const int* __restrict__ flag)
{
    const int f32 = *flag;
    int id = blockIdx.x;
    int proj = id >> 8;            // 0=q,1=k,2=v
    int rem  = id & 255;
    int b  = rem >> 5;
    int ot = (rem >> 2) & 7;       // o-tile (64 outputs = 8 c x 8 h)
    int nt = rem & 3;              // n-tile (64 tokens)

    __shared__ __align__(16) u16 SB[16384];   // 32 KB: 4 bf16 tiles, then EP overlay
    const int WHO = 0, WLO = 4096, XHO = 8192, XLO = 12288;

    int t = threadIdx.x;
    int l = t & 63, w = t >> 6;
    int quad = l >> 4, col = l & 15;
    const int lswz2 = l ^ (((l >> 4) & 1) << 1);

    const u16* Wh  = WCh + ((size_t)proj * 512 + ot * 64) * 256;
    const u16* Wlo = WCl + ((size_t)proj * 512 + ot * 64) * 256;
    int inp = (proj == 0) ? 0 : 1;
    const u16* Xh  = XTh + (((size_t)(inp * 8 + b)) * 256 + nt * 64) * 256;
    const u16* Xlo = XTl + (((size_t)(inp * 8 + b)) * 256 + nt * 64) * 256;

    f32x4 acc[4];
#pragma unroll
    for (int n4 = 0; n4 < 4; ++n4) { acc[n4][0]=0.f; acc[n4][1]=0.f; acc[n4][2]=0.f; acc[n4][3]=0.f; }

    for (int c4 = 0; c4 < 4; ++c4) {
        __syncthreads();                       // prev chunk reads done
#pragma unroll
        for (int it = 0; it < 2; ++it) {
            int g = it * 256 + t;
            int row = g >> 3, cc = g & 7;
            int tt = row >> 4, klo = row & 15, kch = cc >> 2, qs = cc & 3;
            int pos = qs * 16 + (klo ^ ((qs & 1) << 1) ^ (kch << 2));
            int off = ((tt * 2 + kch) * 64 + pos) * 8;
            size_t src = (size_t)row * 256 + c4 * 64 + cc * 8;
            *(U32x4*)&SB[WHO + off] = *(const U32x4*)&Wh[src];
            *(U32x4*)&SB[WLO + off] = *(const U32x4*)&Wlo[src];
            *(U32x4*)&SB[XHO + off] = *(const U32x4*)&Xh[src];
            *(U32x4*)&SB[XLO + off] = *(const U32x4*)&Xlo[src];
        }
        __syncthreads();

        int sA0 = ((w * 2 + 0) * 64 + lswz2) * 8;
        int sA1 = ((w * 2 + 1) * 64 + (lswz2 ^ 4)) * 8;
        bf16x8 aH0 = *(const bf16x8*)&SB[WHO + sA0];
        bf16x8 aH1 = *(const bf16x8*)&SB[WHO + sA1];
        bf16x8 aL0 = *(const bf16x8*)&SB[WLO + sA0];
        bf16x8 aL1 = *(const bf16x8*)&SB[WLO + sA1];
#pragma unroll
        for (int n4 = 0; n4 < 4; ++n4) {
            int sB0 = ((n4 * 2 + 0) * 64 + lswz2) * 8;
            int sB1 = ((n4 * 2 + 1) * 64 + (lswz2 ^ 4)) * 8;
            bf16x8 bH0 = *(const bf16x8*)&SB[XHO + sB0];
            bf16x8 bH1 = *(const bf16x8*)&SB[XHO + sB1];
            bf16x8 bL0 = *(const bf16x8*)&SB[XLO + sB0];
            bf16x8 bL1 = *(const bf16x8*)&SB[XLO + sB1];
            acc[n4] = __builtin_amdgcn_mfma_f32_16x16x32_bf16(aH0, bH0, acc[n4], 0, 0, 0);
            acc[n4] = __builtin_amdgcn_mfma_f32_16x16x32_bf16(aH1, bH1, acc[n4], 0, 0, 0);
            acc[n4] = __builtin_amdgcn_mfma_f32_16x16x32_bf16(aL0, bH0, acc[n4], 0, 0, 0);
            acc[n4] = __builtin_amdgcn_mfma_f32_16x16x32_bf16(aL1, bH1, acc[n4], 0, 0, 0);
            acc[n4] = __builtin_amdgcn_mfma_f32_16x16x32_bf16(aH0, bL0, acc[n4], 0, 0, 0);
            acc[n4] = __builtin_amdgcn_mfma_f32_16x16x32_bf16(aH1, bL1, acc[n4], 0, 0, 0);
        }
    }
    __syncthreads();                           // tiles dead; EP overlays SB

    // ---- epilogue: acc -> EP[o_local][n_local] fp32 (+bias) ----
    float (*EP)[68] = (float (*)[68])SB;
    const u16* bias = (proj == 0) ? bq : (proj == 1) ? bk : bv;
#pragma unroll
    for (int r = 0; r < 4; ++r) {
        int ol = w * 16 + quad * 4 + r;
        float bb = ld(bias, ot * 64 + ol, f32);
#pragma unroll
        for (int n4 = 0; n4 < 4; ++n4)
            EP[ol][n4 * 16 + col] = acc[n4][r] + bb;
    }
    __syncthreads();

    if (proj < 2) {
        u16* OUT = (proj == 0) ? Qg : Kg;
        int hh = t >> 5;
        int nb = t & 31;
#pragma unroll
        for (int p = 0; p < 2; ++p) {
            int nn = nb + 32 * p;
            u32 pk[4];
#pragma unroll
            for (int e = 0; e < 4; ++e) {
                u16 lo = f2bf(EP[(2 * e) * 8 + hh][nn]);
                u16 hi = f2bf(EP[(2 * e + 1) * 8 + hh][nn]);
                pk[e] = (u32)lo | ((u32)hi << 16);
            }
            U32x4 v; v.x = pk[0]; v.y = pk[1]; v.z = pk[2]; v.w = pk[3];
            *(U32x4*)&OUT[((size_t)((hh * 8 + b) * 256) + nt * 64 + nn) * 64 + ot * 8] = v;
        }
    } else {
        int rr = t >> 2;
        int hh = rr & 7, cl = rr >> 3;
        int nq = t & 3;
        u32 pk[8];
#pragma unroll
        for (int e = 0; e < 8; ++e) {
            u16 lo = f2bf(EP[cl * 8 + hh][nq * 16 + 2 * e]);
            u16 hi = f2bf(EP[cl * 8 + hh][nq * 16 + 2 * e + 1]);
            pk[e] = (u32)lo | ((u32)hi << 16);
        }
        size_t base = ((size_t)((hh * 8 + b) * 64) + ot * 8 + cl) * 256 + nt * 64 + nq * 16;
        U32x4 v0; v0.x = pk[0]; v0.y = pk[1]; v0.z = pk[2]; v0.w = pk[3];
        U32x4 v1; v1.x = pk[4]; v1.y = pk[5]; v1.z = pk[6]; v1.w = pk[7];
        *(U32x4*)&Vg[base]     = v0;
        *(U32x4*)&Vg[base + 8] = v1;
    }
}

// ---- softmax + in-register P build (verified round-2 code) --------------------
__device__ __forceinline__ void softmax_p(f32x4 (&Sfr)[16], bf16x8 (&pf)[8]) {
    float inv;
    {
        float m = Sfr[0][0];
#pragma unroll
        for (int tt = 0; tt < 16; ++tt)
#pragma unroll
            for (int r = 0; r < 4; ++r) m = fmaxf(m, Sfr[tt][r]);
        m = fmaxf(m, __shfl_xor(m, 16));
        m = fmaxf(m, __shfl_xor(m, 32));
        float s = 0.f;
#pragma unroll
        for (int tt = 0; tt < 16; ++tt)
#pragma unroll
            for (int r = 0; r < 4; ++r) {
                float e = __expf(Sfr[tt][r] - m);
                Sfr[tt][r] = e; s += e;
            }
        s += __shfl_xor(s, 16);
        s += __shfl_xor(s, 32);
        inv = 1.f / s;
    }
#pragma unroll
    for (int ch = 0; ch < 8; ++ch) {
        float a0 = Sfr[2*ch  ][0]*inv, a1 = Sfr[2*ch  ][1]*inv;
        float a2 = Sfr[2*ch  ][2]*inv, a3 = Sfr[2*ch  ][3]*inv;
        float b0 = Sfr[2*ch+1][0]*inv, b1 = Sfr[2*ch+1][1]*inv;
        float b2 = Sfr[2*ch+1][2]*inv, b3 = Sfr[2*ch+1][3]*inv;
        u32 u0, u1, v0, v1;
        asm("v_cvt_pk_bf16_f32 %0, %1, %2" : "=v"(u0) : "v"(a0), "v"(a1));
        asm("v_cvt_pk_bf16_f32 %0, %1, %2" : "=v"(u1) : "v"(a2), "v"(a3));
        asm("v_cvt_pk_bf16_f32 %0, %1, %2" : "=v"(v0) : "v"(b0), "v"(b1));
        asm("v_cvt_pk_bf16_f32 %0, %1, %2" : "=v"(v1) : "v"(b2), "v"(b3));
        asm("v_permlane32_swap_b32 %0, %1" : "+v"(u0), "+v"(v0));
        asm("v_permlane16_swap_b32 %0, %1" : "+v"(u0), "+v"(v0));
        asm("v_permlane32_swap_b32 %0, %1" : "+v"(u1), "+v"(v1));
        asm("v_permlane16_swap_b32 %0, %1" : "+v"(u1), "+v"(v1));
        union { u32 wd[4]; bf16x8 hB; } pu;
        pu.wd[0] = u0; pu.wd[1] = u1; pu.wd[2] = v0; pu.wd[3] = v1;
        pf[ch] = pu.hB;
    }
}

// ---------------- K2: cross-batch attention, MFMA 16x16x32 bf16 ----------------
// Round-8 = round-7 resubmitted (infra failure, kernel never measured):
// r3-proven grid (512 blocks, 4 kb tiles, 2 Oph slabs) + XCD-local decode
// (bid&7 = h) + T14 pipelined staging (K(kb+1) issued after QK^T; V(kb)
// issued after K-stage barrier; ds_write late from registers).
__global__ __launch_bounds__(256) void k_attn(
    const u16* __restrict__ Qg, const u16* __restrict__ Kg,
    const u16* __restrict__ Vg, float* __restrict__ Oph)
{
    int bid = blockIdx.x;
    int h      = bid & 7;          // XCD id == head
    int slot   = bid >> 3;         // 0..63
    int kbg    = slot >> 5;        // 0..1
    int member = slot & 31;
    int b      = member >> 2;
    int ntq    = member & 3;

    int t = threadIdx.x;
    int l = t & 63, w = t >> 6;
    int quad = l >> 4, col = l & 15;

    __shared__ __align__(16) u16 S[16384];   // 32 KB: K-tile, then V-tile (reused)

    int q = ntq*64 + w*16 + col;
    const size_t qrow = ((size_t)(h*8 + b)*256 + q)*64;
    bf16x8 qf0 = *(const bf16x8*)&Qg[qrow +  0 + quad*8];
    bf16x8 qf1 = *(const bf16x8*)&Qg[qrow + 32 + quad*8];

    const int lswz2 = l ^ (((l >> 4) & 1) << 1);   // K read un-swizzle
    const int lswz4 = l ^ (((l >> 4) & 1) << 2);   // V read un-swizzle (pre ^ch)

    f32x4 Oacc[4];
#pragma unroll
    for (int ct = 0; ct < 4; ++ct) { Oacc[ct][0]=0.f; Oacc[ct][1]=0.f; Oacc[ct][2]=0.f; Oacc[ct][3]=0.f; }

    U32x4 kreg[8], vreg[8];

    // ---- prologue: issue K(kb=first) loads ----
    {
        const size_t kbase = (size_t)(h*8 + kbg*4) * 256 * 64;
#pragma unroll
        for (int i = 0; i < 8; ++i) {
            int g = i*256 + t;
            kreg[i] = *(const U32x4*)&Kg[kbase + (size_t)(g >> 3)*64 + (g & 7)*8];
        }
    }

    for (int kb2 = 0; kb2 < 4; ++kb2) {
        int kb = kbg*4 + kb2;
        __syncthreads();                       // prev PV reads done; S free
        // ---- write K from regs (swizzled dst) ----
#pragma unroll
        for (int i = 0; i < 8; ++i) {
            int g = i*256 + t;
            int key = g >> 3, cc = g & 7;
            int tt = key >> 4, klo = key & 15, kc = cc >> 2, qs = cc & 3;
            int pos = qs*16 + (klo ^ ((qs & 1) << 1) ^ (kc << 2));
            *(U32x4*)&S[(size_t)(((tt*2 + kc)*64) + pos)*8] = kreg[i];
        }
        // ---- issue V(kb) loads (in flight across QK+softmax) ----
        {
            const size_t vbase = (size_t)(h*8 + kb) * 64 * 256;
#pragma unroll
            for (int i = 0; i < 8; ++i) {
                int g = i*256 + t;
                vreg[i] = *(const U32x4*)&Vg[vbase + (size_t)(g >> 5)*256 + (g & 31)*8];
            }
        }
        __syncthreads();                       // K staged

        // ---- QK^T, SWAPPED operands: Sfr[tt][r] = S[key=tt*16+quad*4+r][q=col]
        f32x4 Sfr[16];
#pragma unroll
        for (int tt = 0; tt < 16; ++tt) { Sfr[tt][0]=0.f; Sfr[tt][1]=0.f; Sfr[tt][2]=0.f; Sfr[tt][3]=0.f; }
#pragma unroll
        for (int tt = 0; tt < 16; ++tt) {
            bf16x8 k0 = *(const bf16x8*)&S[(size_t)((tt*2 + 0)*64 + lswz2)*8];
            bf16x8 k1 = *(const bf16x8*)&S[(size_t)((tt*2 + 1)*64 + (lswz2 ^ 4))*8];
            Sfr[tt] = __builtin_amdgcn_mfma_f32_16x16x32_bf16(k0, qf0, Sfr[tt], 0, 0, 0);
            Sfr[tt] = __builtin_amdgcn_mfma_f32_16x16x32_bf16(k1, qf1, Sfr[tt], 0, 0, 0);
        }

        // ---- issue K(kb+1) loads (hidden under softmax + PV) ----
        if (kb2 < 3) {
            const size_t kbase = (size_t)(h*8 + kb + 1) * 256 * 64;
#pragma unroll
            for (int i = 0; i < 8; ++i) {
                int g = i*256 + t;
                kreg[i] = *(const U32x4*)&Kg[kbase + (size_t)(g >> 3)*64 + (g & 7)*8];
            }
        }

        bf16x8 pf[8];
        softmax_p(Sfr, pf);
        __syncthreads();                       // all K reads done; S free for V

        // ---- write V from regs (swizzled dst) ----
#pragma unroll
        for (int i = 0; i < 8; ++i) {
            int g = i*256 + t;
            int cg = g >> 5, k16 = g & 31;
            int ct = cg >> 4, clo = cg & 15, ch = k16 >> 2, qs = k16 & 3;
            int pos = (qs*16 + clo) ^ ch ^ ((qs & 1) << 2);
            *(U32x4*)&S[(size_t)(((ch*4 + ct)*64) + pos)*8] = vreg[i];
        }
        __syncthreads();                       // V staged

        // ---- PV ----
#pragma unroll
        for (int ch = 0; ch < 8; ++ch)
#pragma unroll
            for (int ct = 0; ct < 4; ++ct) {
                bf16x8 vb = *(const bf16x8*)&S[(size_t)(((ch*4 + ct)*64) + (lswz4 ^ ch))*8];
                Oacc[ct] = __builtin_amdgcn_mfma_f32_16x16x32_bf16(pf[ch], vb, Oacc[ct], 0, 0, 0);
            }
    }

    // ---- write O partial to slab kbg (plain stores) ----
    float* Op = Oph + (size_t)kbg * ((size_t)BB * EMB * NT);
    const size_t obase = (size_t)(h*8 + b) * 256 * 64;
    int n0 = ntq*64 + w*16 + quad*4;
#pragma unroll
    for (int ct = 0; ct < 4; ++ct)
#pragma unroll
        for (int r = 0; r < 4; ++r)
            Op[obase + (size_t)(n0 + r)*64 + ct*16 + col] = Oacc[ct][r];
}

// ---------------- K3: Wa projection + bias + residual (scalar, pipelined) ------
// r3 traffic (2-slab sum) + r5-validated XCD-local decode (it=id>>6, tt=id&63).
__global__ __launch_bounds__(256) void k_proj_res(
    const float* __restrict__ Oph, const u16* __restrict__ Wa,
    const u16* __restrict__ ba, const u16* __restrict__ x1,
    float* __restrict__ Ap, const int* __restrict__ flag)
{
    const int f32 = *flag;
    int id = blockIdx.x;
    int it = id >> 6;           // i tile 0..3 (64 i each)
    int tt = id & 63;           // 32-token tiles
    int tok0 = tt * 32;
    int b  = tok0 >> 8;
    int n0 = tok0 & 255;

    __shared__ float Was[64][68];  // Was[e][i]
    __shared__ float Os[64][36];   // Os[e][tok32]

    int t = threadIdx.x;
    int lane64 = t & 63, quad = t >> 6;
    int ig = t & 15;
    int tg = t >> 4;

    int tk = t & 31;
    int hh = t >> 5;

    const size_t SLAB = (size_t)BB * EMB * NT;

    float wreg[16];
    float oreg[8];

    {
#pragma unroll
        for (int p = 0; p < 16; ++p) {
            int i = quad + 4*p;
            wreg[p] = ld(Wa, (size_t)(it*64 + i)*EMB + 0*64 + lane64, f32);
        }
        const float* src = &Oph[(((size_t)(hh*8 + b))*256 + n0 + tk)*64 + 0*8];
        float4 v0 = *(const float4*)&src[0];
        float4 v1 = *(const float4*)&src[4];
        float4 u0 = *(const float4*)&src[SLAB];
        float4 u1 = *(const float4*)&src[SLAB + 4];
        oreg[0]=v0.x+u0.x; oreg[1]=v0.y+u0.y; oreg[2]=v0.z+u0.z; oreg[3]=v0.w+u0.w;
        oreg[4]=v1.x+u1.x; oreg[5]=v1.y+u1.y; oreg[6]=v1.z+u1.z; oreg[7]=v1.w+u1.w;
    }

    float acc[8];
#pragma unroll
    for (int j = 0; j < 8; ++j) acc[j] = 0.f;

    for (int kc = 0; kc < 8; ++kc) {
        __syncthreads();
#pragma unroll
        for (int p = 0; p < 16; ++p)
            Was[lane64][quad + 4*p] = wreg[p];
#pragma unroll
        for (int e = 0; e < 8; ++e)
            Os[e*8 + hh][tk] = oreg[e];
        __syncthreads();

        if (kc < 7) {
            int kn = kc + 1;
#pragma unroll
            for (int p = 0; p < 16; ++p) {
                int i = quad + 4*p;
                wreg[p] = ld(Wa, (size_t)(it*64 + i)*EMB + kn*64 + lane64, f32);
            }
            const float* src = &Oph[(((size_t)(hh*8 + b))*256 + n0 + tk)*64 + kn*8];
            float4 v0 = *(const float4*)&src[0];
            float4 v1 = *(const float4*)&src[4];
            float4 u0 = *(const float4*)&src[SLAB];
            float4 u1 = *(const float4*)&src[SLAB + 4];
            oreg[0]=v0.x+u0.x; oreg[1]=v0.y+u0.y; oreg[2]=v0.z+u0.z; oreg[3]=v0.w+u0.w;
            oreg[4]=v1.x+u1.x; oreg[5]=v1.y+u1.y; oreg[6]=v1.z+u1.z; oreg[7]=v1.w+u1.w;
        }

#pragma unroll 8
        for (int o = 0; o < 64; ++o) {
            float4 w4 = *(const float4*)&Was[o][ig*4];
            float2 t2 = *(const float2*)&Os[o][tg*2];
            acc[0] += w4.x*t2.x; acc[1] += w4.y*t2.x;
            acc[2] += w4.z*t2.x; acc[3] += w4.w*t2.x;
            acc[4] += w4.x*t2.y; acc[5] += w4.y*t2.y;
            acc[6] += w4.z*t2.y; acc[7] += w4.w*t2.y;
        }
    }

    int i0 = it*64 + ig*4;
    float ba0 = ld(ba, i0+0, f32), ba1 = ld(ba, i0+1, f32);
    float ba2 = ld(ba, i0+2, f32), ba3 = ld(ba, i0+3, f32);
#pragma unroll
    for (int jt = 0; jt < 2; ++jt) {
        int token = tok0 + tg*2 + jt;
        int n = n0 + tg*2 + jt;
        float4 v;
        v.x = acc[jt*4+0] + ba0 + ld(x1, ((size_t)b*CIN + i0+0)*NT + n, f32);
        v.y = acc[jt*4+1] + ba1 + ld(x1, ((size_t)b*CIN + i0+1)*NT + n, f32);
        v.z = acc[jt*4+2] + ba2 + ld(x1, ((size_t)b*CIN + i0+2)*NT + n, f32);
        v.w = acc[jt*4+3] + ba3 + ld(x1, ((size_t)b*CIN + i0+3)*NT + n, f32);
        *(float4*)&Ap[(size_t)token*CIN + i0] = v;
    }
}

// ---------------- K4: LayerNorm + Linear + ReLU -> out -------------------------
// (r3-measured shape: 256 blocks, 8 tokens/block)
__global__ void k_ln_out(
    const float* __restrict__ Ap, const u16* __restrict__ ln_g,
    const u16* __restrict__ ln_b, const u16* __restrict__ Wl,
    const u16* __restrict__ bl, u16* __restrict__ out,
    const int* __restrict__ flag)
{
    const int f32 = *flag;
    int tok0 = blockIdx.x * 8;
    int b  = tok0 >> 8;
    int n0 = tok0 & 255;

    __shared__ float At[8][260];

    int t = threadIdx.x;
#pragma unroll
    for (int k = 0; k < 8; ++k)
        At[k][t] = Ap[((size_t)tok0 + k)*CIN + t];
    __syncthreads();

    {   // LN: 32 lanes per token, 8 i-values each
        int kk = t >> 5, lme = t & 31;
        float s = 0.f, s2 = 0.f;
#pragma unroll
        for (int ii = 0; ii < 8; ++ii) { float v = At[kk][lme + 32*ii]; s += v; s2 += v*v; }
#pragma unroll
        for (int off = 1; off < 32; off <<= 1) { s += __shfl_xor(s, off); s2 += __shfl_xor(s2, off); }
        float mu   = s  * (1.f/256.f);
        float var  = s2 * (1.f/256.f) - mu*mu;
        float rstd = rsqrtf(var + 1e-5f);
#pragma unroll
        for (int ii = 0; ii < 8; ++ii) {
            int i = lme + 32*ii;
            float v = At[kk][i];
            At[kk][i] = (v - mu) * rstd * ld(ln_g, i, f32) + ld(ln_b, i, f32);
        }
    }
    __syncthreads();

    int j = t;
    float acc[8];
#pragma unroll
    for (int k = 0; k < 8; ++k) acc[k] = 0.f;

    if (f32) {
        const float* wrow = (const float*)Wl + (size_t)j*CIN;
#pragma unroll 2
        for (int i4 = 0; i4 < 64; ++i4) {
            float4 w4 = *(const float4*)&wrow[4*i4];
#pragma unroll
            for (int k = 0; k < 8; ++k) {
                float4 a = *(const float4*)&At[k][4*i4];
                acc[k] += w4.x*a.x + w4.y*a.y + w4.z*a.z + w4.w*a.w;
            }
        }
    } else {
        const u32* wrow = (const u32*)(Wl + (size_t)j*CIN);
#pragma unroll 2
        for (int i4 = 0; i4 < 64; ++i4) {
            u32 w01 = wrow[2*i4+0], w23 = wrow[2*i4+1];
            float c0 = bf2f((u16)(w01 & 0xFFFFu)), c1 = bf2f((u16)(w01 >> 16));
            float c2 = bf2f((u16)(w23 & 0xFFFFu)), c3 = bf2f((u16)(w23 >> 16));
#pragma unroll
            for (int k = 0; k < 8; ++k) {
                float4 a = *(const float4*)&At[k][4*i4];
                acc[k] += c0*a.x + c1*a.y + c2*a.z + c3*a.w;
            }
        }
    }

    float blv = ld(bl, j, f32);
    size_t obase = ((size_t)b*CIN + j)*NT + n0;
    if (f32) {
        float* o32 = (float*)out;
#pragma unroll
        for (int k = 0; k < 8; ++k)
            o32[obase + k] = fmaxf(acc[k] + blv, 0.f);
    } else {
        u32 pk[4];
#pragma unroll
        for (int k = 0; k < 4; ++k) {
            float f0 = fmaxf(acc[2*k+0] + blv, 0.f);
            float f1 = fmaxf(acc[2*k+1] + blv, 0.f);
            pk[k] = (u32)f2bf(f0) | ((u32)f2bf(f1) << 16);
        }
        U32x4 a0; a0.x = pk[0]; a0.y = pk[1]; a0.z = pk[2]; a0.w = pk[3];
        *(U32x4*)(out + obase) = a0;
    }
}

// ---------------------------------------------------------------
extern "C" void kernel_launch(void* const* d_in, const int* in_sizes, int n_in,
                              void* d_out, int out_size, void* d_ws, size_t ws_size,
                              hipStream_t stream)
{
    const u16* x1   = (const u16*)d_in[0];
    const u16* x2   = (const u16*)d_in[1];
    const u16* Wq   = (const u16*)d_in[2];
    const u16* bq   = (const u16*)d_in[3];
    const u16* Wk   = (const u16*)d_in[4];
    const u16* bk   = (const u16*)d_in[5];
    const u16* Wv   = (const u16*)d_in[6];
    const u16* bv   = (const u16*)d_in[7];
    const u16* Wa   = (const u16*)d_in[8];
    const u16* ba   = (const u16*)d_in[9];
    const u16* ln_g = (const u16*)d_in[10];
    const u16* ln_b = (const u16*)d_in[11];
    const u16* Wl   = (const u16*)d_in[12];
    const u16* bl   = (const u16*)d_in[13];
    u16* out = (u16*)d_out;

    int* flag = (int*)d_ws;
    u16* Qg = (u16*)d_ws + 32;                       // +64 B
    u16* Kg = Qg + (size_t)BB*EMB*NT;                // 1M u16 each
    u16* Vg = Kg + (size_t)BB*EMB*NT;
    float* Oph = (float*)(Vg + (size_t)BB*EMB*NT);   // 2 slabs of 4 MB
    float* Ap  = Oph + 4*(size_t)BB*EMB*NT;
    u16* XTh = (u16*)(Ap + (size_t)BB*NT*CIN);       // 2*8*256*256 u16
    u16* XTl = XTh + (size_t)2*BB*NT*CIN;
    u16* WCh = XTl + (size_t)2*BB*NT*CIN;            // 3*512*256 u16
    u16* WCl = WCh + (size_t)3*EMB*CIN;

    k_xpose   <<<268, 256, 0, stream>>>(x1, x2, Wq, Wk, Wv, XTh, XTl, WCh, WCl, flag);
    k_qkv     <<<768, 256, 0, stream>>>(XTh, XTl, WCh, WCl, bq, bk, bv, Qg, Kg, Vg, flag);
    k_attn    <<<512, 256, 0, stream>>>(Qg, Kg, Vg, Oph);
    k_proj_res<<<256, 256, 0, stream>>>(Oph, Wa, ba, x1, Ap, flag);
    k_ln_out  <<<256, 256, 0, stream>>>(Ap, ln_g, ln_b, Wl, bl, out, flag);
}

// Round 9
// 182.845 us; speedup vs baseline: 1.1908x; 1.1908x over previous
//
#include <hip/hip_runtime.h>

typedef unsigned short u16;
typedef unsigned int   u32;
typedef __attribute__((ext_vector_type(8))) short bf16x8;
typedef __attribute__((ext_vector_type(4))) float f32x4;

#define BB   8
#define CIN  256
#define NT   256
#define EMB  512
#define NH   8

// ---- bf16 <-> f32 via raw bits ----
__device__ __forceinline__ float bf2f(u16 b) {
    union { u32 u; float f; } v; v.u = ((u32)b) << 16; return v.f;
}
__device__ __forceinline__ u16 f2bf(float f) {
    union { float f; u32 u; } v; v.f = f;
    u32 r = v.u + 0x7FFFu + ((v.u >> 16) & 1u);  // RNE
    return (u16)(r >> 16);
}
__device__ __forceinline__ float ld(const u16* base, size_t idx, int f32) {
    return f32 ? ((const float*)base)[idx] : bf2f(base[idx]);
}

struct alignas(16) U32x4 { u32 x, y, z, w; };

// ---------------- K0: transpose X + split-bf16 convert X and W -----------------
// (r3-measured body + flag write folded in, validated rounds 4-8)
__global__ void k_xpose(
    const u16* __restrict__ x1, const u16* __restrict__ x2,
    const u16* __restrict__ Wq, const u16* __restrict__ Wk, const u16* __restrict__ Wv,
    u16* __restrict__ XTh, u16* __restrict__ XTl,
    u16* __restrict__ WCh, u16* __restrict__ WCl,
    int* __restrict__ flag)
{
    __shared__ int cnt;
    __shared__ float T[64][65];
    int t = threadIdx.x;
    if (t == 0) cnt = 0;
    __syncthreads();
    {
        int local = 0;
        for (int j = t * 16; j < t * 16 + 16; j += 2) {
            u16 w = x1[j];
            int e = (w >> 7) & 0xFF;
            if (e >= 100 && e <= 145) local++;
        }
        atomicAdd(&cnt, local);
    }
    __syncthreads();
    const int f32 = (cnt >= 1200) ? 0 : 1;

    int bid = blockIdx.x;
    if (bid == 0 && t == 0) *flag = f32;

    if (bid < 256) {
        // X transpose: one 64x64 subtile per block
        int inp = bid >> 7, b = (bid >> 4) & 7, ks = (bid >> 2) & 3, ns = bid & 3;
        const u16* X = inp ? x2 : x1;
#pragma unroll
        for (int p = 0; p < 4; ++p) {
            int kk = p * 16 + (t >> 4);
            int nn = (t & 15) * 4;
#pragma unroll
            for (int j = 0; j < 4; ++j)
                T[kk][nn + j] = ld(X, ((size_t)b * CIN + ks * 64 + kk) * NT + ns * 64 + nn + j, f32);
        }
        __syncthreads();
#pragma unroll
        for (int it = 0; it < 2; ++it) {
            int g = it * 256 + t;
            int nn = g >> 3, kg = g & 7;
            u32 hw[4], lw[4];
#pragma unroll
            for (int e = 0; e < 4; ++e) {
                float va = T[kg * 8 + 2 * e][nn];
                float vb = T[kg * 8 + 2 * e + 1][nn];
                u16 ha = f2bf(va), hb = f2bf(vb);
                u16 la = f2bf(va - bf2f(ha)), lb = f2bf(vb - bf2f(hb));
                hw[e] = (u32)ha | ((u32)hb << 16);
                lw[e] = (u32)la | ((u32)lb << 16);
            }
            size_t dst = (((size_t)(inp * 8 + b) * 256) + ns * 64 + nn) * 256 + ks * 64 + kg * 8;
            U32x4 H; H.x = hw[0]; H.y = hw[1]; H.z = hw[2]; H.w = hw[3];
            U32x4 L; L.x = lw[0]; L.y = lw[1]; L.z = lw[2]; L.w = lw[3];
            *(U32x4*)&XTh[dst] = H;
            *(U32x4*)&XTl[dst] = L;
        }
    } else {
        // W convert: 128 rows per block
        int wb = bid - 256;                 // 0..11
        int proj = wb >> 2, qtr = wb & 3;
        const u16* W = (proj == 0) ? Wq : (proj == 1) ? Wk : Wv;
#pragma unroll
        for (int it = 0; it < 16; ++it) {
            int g = it * 256 + t;
            int row = g >> 5, kg = g & 31;
            int o = qtr * 128 + row;
            u32 hw[4], lw[4];
#pragma unroll
            for (int e = 0; e < 4; ++e) {
                float va = ld(W, (size_t)o * CIN + kg * 8 + 2 * e, f32);
                float vb = ld(W, (size_t)o * CIN + kg * 8 + 2 * e + 1, f32);
                u16 ha = f2bf(va), hb = f2bf(vb);
                u16 la = f2bf(va - bf2f(ha)), lb = f2bf(vb - bf2f(hb));
                hw[e] = (u32)ha | ((u32)hb << 16);
                lw[e] = (u32)la | ((u32)lb << 16);
            }
            size_t dst = ((size_t)(proj * 512 + o)) * 256 + kg * 8;
            U32x4 H; H.x = hw[0]; H.y = hw[1]; H.z = hw[2]; H.w = hw[3];
            U32x4 L; L.x = lw[0]; L.y = lw[1]; L.z = lw[2]; L.w = lw[3];
            *(U32x4*)&WCh[dst] = H;
            *(U32x4*)&WCl[dst] = L;
        }
    }
}

// ---------------- K1: QKV projections, MFMA 16x16x32 bf16 (split-precision) ----
// (r3-measured)
__global__ __launch_bounds__(256) void k_qkv(
    const u16* __restrict__ XTh, const u16* __restrict__ XTl,
    const u16* __restrict__ WCh, const u16* __restrict__ WCl,
    const u16* __restrict__ bq, const u16* __restrict__ bk, const u16* __restrict__ bv,
    u16* __restrict__ Qg, u16* __restrict__ Kg, u16* __restrict__ Vg,
    const int* __restrict__ flag)
{
    const int f32 = *flag;
    int id = blockIdx.x;
    int proj = id >> 8;            // 0=q,1=k,2=v
    int rem  = id & 255;
    int b  = rem >> 5;
    int ot = (rem >> 2) & 7;       // o-tile (64 outputs = 8 c x 8 h)
    int nt = rem & 3;              // n-tile (64 tokens)

    __shared__ __align__(16) u16 SB[16384];   // 32 KB: 4 bf16 tiles, then EP overlay
    const int WHO = 0, WLO = 4096, XHO = 8192, XLO = 12288;

    int t = threadIdx.x;
    int l = t & 63, w = t >> 6;
    int quad = l >> 4, col = l & 15;
    const int lswz2 = l ^ (((l >> 4) & 1) << 1);

    const u16* Wh  = WCh + ((size_t)proj * 512 + ot * 64) * 256;
    const u16* Wlo = WCl + ((size_t)proj * 512 + ot * 64) * 256;
    int inp = (proj == 0) ? 0 : 1;
    const u16* Xh  = XTh + (((size_t)(inp * 8 + b)) * 256 + nt * 64) * 256;
    const u16* Xlo = XTl + (((size_t)(inp * 8 + b)) * 256 + nt * 64) * 256;

    f32x4 acc[4];
#pragma unroll
    for (int n4 = 0; n4 < 4; ++n4) { acc[n4][0]=0.f; acc[n4][1]=0.f; acc[n4][2]=0.f; acc[n4][3]=0.f; }

    for (int c4 = 0; c4 < 4; ++c4) {
        __syncthreads();                       // prev chunk reads done
#pragma unroll
        for (int it = 0; it < 2; ++it) {
            int g = it * 256 + t;
            int row = g >> 3, cc = g & 7;
            int tt = row >> 4, klo = row & 15, kch = cc >> 2, qs = cc & 3;
            int pos = qs * 16 + (klo ^ ((qs & 1) << 1) ^ (kch << 2));
            int off = ((tt * 2 + kch) * 64 + pos) * 8;
            size_t src = (size_t)row * 256 + c4 * 64 + cc * 8;
            *(U32x4*)&SB[WHO + off] = *(const U32x4*)&Wh[src];
            *(U32x4*)&SB[WLO + off] = *(const U32x4*)&Wlo[src];
            *(U32x4*)&SB[XHO + off] = *(const U32x4*)&Xh[src];
            *(U32x4*)&SB[XLO + off] = *(const U32x4*)&Xlo[src];
        }
        __syncthreads();

        int sA0 = ((w * 2 + 0) * 64 + lswz2) * 8;
        int sA1 = ((w * 2 + 1) * 64 + (lswz2 ^ 4)) * 8;
        bf16x8 aH0 = *(const bf16x8*)&SB[WHO + sA0];
        bf16x8 aH1 = *(const bf16x8*)&SB[WHO + sA1];
        bf16x8 aL0 = *(const bf16x8*)&SB[WLO + sA0];
        bf16x8 aL1 = *(const bf16x8*)&SB[WLO + sA1];
#pragma unroll
        for (int n4 = 0; n4 < 4; ++n4) {
            int sB0 = ((n4 * 2 + 0) * 64 + lswz2) * 8;
            int sB1 = ((n4 * 2 + 1) * 64 + (lswz2 ^ 4)) * 8;
            bf16x8 bH0 = *(const bf16x8*)&SB[XHO + sB0];
            bf16x8 bH1 = *(const bf16x8*)&SB[XHO + sB1];
            bf16x8 bL0 = *(const bf16x8*)&SB[XLO + sB0];
            bf16x8 bL1 = *(const bf16x8*)&SB[XLO + sB1];
            acc[n4] = __builtin_amdgcn_mfma_f32_16x16x32_bf16(aH0, bH0, acc[n4], 0, 0, 0);
            acc[n4] = __builtin_amdgcn_mfma_f32_16x16x32_bf16(aH1, bH1, acc[n4], 0, 0, 0);
            acc[n4] = __builtin_amdgcn_mfma_f32_16x16x32_bf16(aL0, bH0, acc[n4], 0, 0, 0);
            acc[n4] = __builtin_amdgcn_mfma_f32_16x16x32_bf16(aL1, bH1, acc[n4], 0, 0, 0);
            acc[n4] = __builtin_amdgcn_mfma_f32_16x16x32_bf16(aH0, bL0, acc[n4], 0, 0, 0);
            acc[n4] = __builtin_amdgcn_mfma_f32_16x16x32_bf16(aH1, bL1, acc[n4], 0, 0, 0);
        }
    }
    __syncthreads();                           // tiles dead; EP overlays SB

    // ---- epilogue: acc -> EP[o_local][n_local] fp32 (+bias) ----
    float (*EP)[68] = (float (*)[68])SB;
    const u16* bias = (proj == 0) ? bq : (proj == 1) ? bk : bv;
#pragma unroll
    for (int r = 0; r < 4; ++r) {
        int ol = w * 16 + quad * 4 + r;
        float bb = ld(bias, ot * 64 + ol, f32);
#pragma unroll
        for (int n4 = 0; n4 < 4; ++n4)
            EP[ol][n4 * 16 + col] = acc[n4][r] + bb;
    }
    __syncthreads();

    if (proj < 2) {
        u16* OUT = (proj == 0) ? Qg : Kg;
        int hh = t >> 5;
        int nb = t & 31;
#pragma unroll
        for (int p = 0; p < 2; ++p) {
            int nn = nb + 32 * p;
            u32 pk[4];
#pragma unroll
            for (int e = 0; e < 4; ++e) {
                u16 lo = f2bf(EP[(2 * e) * 8 + hh][nn]);
                u16 hi = f2bf(EP[(2 * e + 1) * 8 + hh][nn]);
                pk[e] = (u32)lo | ((u32)hi << 16);
            }
            U32x4 v; v.x = pk[0]; v.y = pk[1]; v.z = pk[2]; v.w = pk[3];
            *(U32x4*)&OUT[((size_t)((hh * 8 + b) * 256) + nt * 64 + nn) * 64 + ot * 8] = v;
        }
    } else {
        int rr = t >> 2;
        int hh = rr & 7, cl = rr >> 3;
        int nq = t & 3;
        u32 pk[8];
#pragma unroll
        for (int e = 0; e < 8; ++e) {
            u16 lo = f2bf(EP[cl * 8 + hh][nq * 16 + 2 * e]);
            u16 hi = f2bf(EP[cl * 8 + hh][nq * 16 + 2 * e + 1]);
            pk[e] = (u32)lo | ((u32)hi << 16);
        }
        size_t base = ((size_t)((hh * 8 + b) * 64) + ot * 8 + cl) * 256 + nt * 64 + nq * 16;
        U32x4 v0; v0.x = pk[0]; v0.y = pk[1]; v0.z = pk[2]; v0.w = pk[3];
        U32x4 v1; v1.x = pk[4]; v1.y = pk[5]; v1.z = pk[6]; v1.w = pk[7];
        *(U32x4*)&Vg[base]     = v0;
        *(U32x4*)&Vg[base + 8] = v1;
    }
}

// ---- softmax + in-register P build (verified round-2 code) --------------------
__device__ __forceinline__ void softmax_p(f32x4 (&Sfr)[16], bf16x8 (&pf)[8]) {
    float inv;
    {
        float m = Sfr[0][0];
#pragma unroll
        for (int tt = 0; tt < 16; ++tt)
#pragma unroll
            for (int r = 0; r < 4; ++r) m = fmaxf(m, Sfr[tt][r]);
        m = fmaxf(m, __shfl_xor(m, 16));
        m = fmaxf(m, __shfl_xor(m, 32));
        float s = 0.f;
#pragma unroll
        for (int tt = 0; tt < 16; ++tt)
#pragma unroll
            for (int r = 0; r < 4; ++r) {
                float e = __expf(Sfr[tt][r] - m);
                Sfr[tt][r] = e; s += e;
            }
        s += __shfl_xor(s, 16);
        s += __shfl_xor(s, 32);
        inv = 1.f / s;
    }
#pragma unroll
    for (int ch = 0; ch < 8; ++ch) {
        float a0 = Sfr[2*ch  ][0]*inv, a1 = Sfr[2*ch  ][1]*inv;
        float a2 = Sfr[2*ch  ][2]*inv, a3 = Sfr[2*ch  ][3]*inv;
        float b0 = Sfr[2*ch+1][0]*inv, b1 = Sfr[2*ch+1][1]*inv;
        float b2 = Sfr[2*ch+1][2]*inv, b3 = Sfr[2*ch+1][3]*inv;
        u32 u0, u1, v0, v1;
        asm("v_cvt_pk_bf16_f32 %0, %1, %2" : "=v"(u0) : "v"(a0), "v"(a1));
        asm("v_cvt_pk_bf16_f32 %0, %1, %2" : "=v"(u1) : "v"(a2), "v"(a3));
        asm("v_cvt_pk_bf16_f32 %0, %1, %2" : "=v"(v0) : "v"(b0), "v"(b1));
        asm("v_cvt_pk_bf16_f32 %0, %1, %2" : "=v"(v1) : "v"(b2), "v"(b3));
        asm("v_permlane32_swap_b32 %0, %1" : "+v"(u0), "+v"(v0));
        asm("v_permlane16_swap_b32 %0, %1" : "+v"(u0), "+v"(v0));
        asm("v_permlane32_swap_b32 %0, %1" : "+v"(u1), "+v"(v1));
        asm("v_permlane16_swap_b32 %0, %1" : "+v"(u1), "+v"(v1));
        union { u32 wd[4]; bf16x8 hB; } pu;
        pu.wd[0] = u0; pu.wd[1] = u1; pu.wd[2] = v0; pu.wd[3] = v1;
        pf[ch] = pu.hB;
    }
}

// ---------------- K2: cross-batch attention, MFMA 16x16x32 bf16 ----------------
// EXACT r3-measured kernel (best total 185.0 us): 512 blocks, 4 kb tiles/block,
// single q-tile (124 VGPR), direct global loads into LDS-staging path (no
// register prefetch — r8 proved the compiler spills staging arrays to scratch),
// O partials -> 2 slabs via plain stores.
__global__ __launch_bounds__(256) void k_attn(
    const u16* __restrict__ Qg, const u16* __restrict__ Kg,
    const u16* __restrict__ Vg, float* __restrict__ Oph)
{
    int bid = blockIdx.x;
    int h   = bid >> 6;
    int kbg = (bid >> 5) & 1;
    int b   = (bid >> 2) & 7;
    int ntq = bid & 3;

    int t = threadIdx.x;
    int l = t & 63, w = t >> 6;
    int quad = l >> 4, col = l & 15;

    __shared__ __align__(16) u16 S[16384];   // 32 KB: K-tile, then V-tile (reused)

    int q = ntq*64 + w*16 + col;
    const size_t qrow = ((size_t)(h*8 + b)*256 + q)*64;
    bf16x8 qf0 = *(const bf16x8*)&Qg[qrow +  0 + quad*8];
    bf16x8 qf1 = *(const bf16x8*)&Qg[qrow + 32 + quad*8];

    const int lswz2 = l ^ (((l >> 4) & 1) << 1);   // K read un-swizzle
    const int lswz4 = l ^ (((l >> 4) & 1) << 2);   // V read un-swizzle (pre ^ch)

    f32x4 Oacc[4];
#pragma unroll
    for (int ct = 0; ct < 4; ++ct) { Oacc[ct][0]=0.f; Oacc[ct][1]=0.f; Oacc[ct][2]=0.f; Oacc[ct][3]=0.f; }

    for (int kb2 = 0; kb2 < 4; ++kb2) {
        int kb = kbg*4 + kb2;
        __syncthreads();                                   // prev PV reads done
        // ---- stage K (8 iters x 256 thr), bank-swizzled ----
        const size_t kbase = (size_t)(h*8 + kb) * 256 * 64;
#pragma unroll
        for (int i = 0; i < 8; ++i) {
            int g = i*256 + t;
            int key = g >> 3, cc = g & 7;
            int tt = key >> 4, klo = key & 15, kc = cc >> 2, qs = cc & 3;
            int pos = qs*16 + (klo ^ ((qs & 1) << 1) ^ (kc << 2));
            U32x4 v = *(const U32x4*)&Kg[kbase + (size_t)key*64 + cc*8];
            *(U32x4*)&S[(size_t)(((tt*2 + kc)*64) + pos)*8] = v;
        }
        __syncthreads();

        // ---- QK^T, SWAPPED operands: Sfr[tt][r] = S[key=tt*16+quad*4+r][q=col]
        f32x4 Sfr[16];
#pragma unroll
        for (int tt = 0; tt < 16; ++tt) { Sfr[tt][0]=0.f; Sfr[tt][1]=0.f; Sfr[tt][2]=0.f; Sfr[tt][3]=0.f; }
#pragma unroll
        for (int tt = 0; tt < 16; ++tt) {
            bf16x8 k0 = *(const bf16x8*)&S[(size_t)((tt*2 + 0)*64 + lswz2)*8];
            bf16x8 k1 = *(const bf16x8*)&S[(size_t)((tt*2 + 1)*64 + (lswz2 ^ 4))*8];
            Sfr[tt] = __builtin_amdgcn_mfma_f32_16x16x32_bf16(k0, qf0, Sfr[tt], 0, 0, 0);
            Sfr[tt] = __builtin_amdgcn_mfma_f32_16x16x32_bf16(k1, qf1, Sfr[tt], 0, 0, 0);
        }

        bf16x8 pf[8];
        softmax_p(Sfr, pf);
        __syncthreads();                                   // all K reads done

        // ---- stage V (swizzled, 8 iters x 256 thr) ----
        const size_t vbase = (size_t)(h*8 + kb) * 64 * 256;
#pragma unroll
        for (int i = 0; i < 8; ++i) {
            int g = i*256 + t;
            int cg = g >> 5, k16 = g & 31;
            int ct = cg >> 4, clo = cg & 15, ch = k16 >> 2, qs = k16 & 3;
            int pos = (qs*16 + clo) ^ ch ^ ((qs & 1) << 2);
            U32x4 v = *(const U32x4*)&Vg[vbase + (size_t)cg*256 + k16*8];
            *(U32x4*)&S[(size_t)(((ch*4 + ct)*64) + pos)*8] = v;
        }
        __syncthreads();

        // ---- PV ----
#pragma unroll
        for (int ch = 0; ch < 8; ++ch)
#pragma unroll
            for (int ct = 0; ct < 4; ++ct) {
                bf16x8 vb = *(const bf16x8*)&S[(size_t)(((ch*4 + ct)*64) + (lswz4 ^ ch))*8];
                Oacc[ct] = __builtin_amdgcn_mfma_f32_16x16x32_bf16(pf[ch], vb, Oacc[ct], 0, 0, 0);
            }
    }

    // ---- write O partial to slab kbg: plain stores ----
    float* Op = Oph + (size_t)kbg * ((size_t)BB * EMB * NT);
    const size_t obase = (size_t)(h*8 + b) * 256 * 64;
    int n0 = ntq*64 + w*16 + quad*4;
#pragma unroll
    for (int ct = 0; ct < 4; ++ct)
#pragma unroll
        for (int r = 0; r < 4; ++r)
            Op[obase + (size_t)(n0 + r)*64 + ct*16 + col] = Oacc[ct][r];
}

// ---------------- K3: Wa projection + bias + residual (scalar, pipelined) ------
// (r3-measured: 256 blocks, tt=id>>2 / it=id&3, 2-slab register sum)
__global__ void k_proj_res(
    const float* __restrict__ Oph, const u16* __restrict__ Wa,
    const u16* __restrict__ ba, const u16* __restrict__ x1,
    float* __restrict__ Ap, const int* __restrict__ flag)
{
    const int f32 = *flag;
    int id = blockIdx.x;
    int tt = id >> 2;           // 0..63 (32-token tiles)
    int it = id & 3;            // i tile 0..3
    int tok0 = tt * 32;
    int b  = tok0 >> 8;
    int n0 = tok0 & 255;

    __shared__ float Was[64][68];  // Was[o][i]
    __shared__ float Os[64][36];   // Os[o][tok32]

    int t = threadIdx.x;
    int lane64 = t & 63, quad = t >> 6;
    int ig = t & 15;
    int tg = t >> 4;

    int tk = t & 31;
    int hh = t >> 5;

    const size_t SLAB = (size_t)BB * EMB * NT;

    float wreg[16];
    float oreg[8];

    {
#pragma unroll
        for (int p = 0; p < 16; ++p) {
            int i = quad + 4*p;
            wreg[p] = ld(Wa, (size_t)(it*64 + i)*EMB + 0*64 + lane64, f32);
        }
        const float* src = &Oph[(((size_t)(hh*8 + b))*256 + n0 + tk)*64 + 0*8];
        float4 v0 = *(const float4*)&src[0];
        float4 v1 = *(const float4*)&src[4];
        float4 u0 = *(const float4*)&src[SLAB];
        float4 u1 = *(const float4*)&src[SLAB + 4];
        oreg[0]=v0.x+u0.x; oreg[1]=v0.y+u0.y; oreg[2]=v0.z+u0.z; oreg[3]=v0.w+u0.w;
        oreg[4]=v1.x+u1.x; oreg[5]=v1.y+u1.y; oreg[6]=v1.z+u1.z; oreg[7]=v1.w+u1.w;
    }

    float acc[8];
#pragma unroll
    for (int j = 0; j < 8; ++j) acc[j] = 0.f;

    for (int kc = 0; kc < 8; ++kc) {
        __syncthreads();
#pragma unroll
        for (int p = 0; p < 16; ++p)
            Was[lane64][quad + 4*p] = wreg[p];
#pragma unroll
        for (int e = 0; e < 8; ++e)
            Os[e*8 + hh][tk] = oreg[e];
        __syncthreads();

        if (kc < 7) {
            int kn = kc + 1;
#pragma unroll
            for (int p = 0; p < 16; ++p) {
                int i = quad + 4*p;
                wreg[p] = ld(Wa, (size_t)(it*64 + i)*EMB + kn*64 + lane64, f32);
            }
            const float* src = &Oph[(((size_t)(hh*8 + b))*256 + n0 + tk)*64 + kn*8];
            float4 v0 = *(const float4*)&src[0];
            float4 v1 = *(const float4*)&src[4];
            float4 u0 = *(const float4*)&src[SLAB];
            float4 u1 = *(const float4*)&src[SLAB + 4];
            oreg[0]=v0.x+u0.x; oreg[1]=v0.y+u0.y; oreg[2]=v0.z+u0.z; oreg[3]=v0.w+u0.w;
            oreg[4]=v1.x+u1.x; oreg[5]=v1.y+u1.y; oreg[6]=v1.z+u1.z; oreg[7]=v1.w+u1.w;
        }

#pragma unroll 8
        for (int o = 0; o < 64; ++o) {
            float4 w4 = *(const float4*)&Was[o][ig*4];
            float2 t2 = *(const float2*)&Os[o][tg*2];
            acc[0] += w4.x*t2.x; acc[1] += w4.y*t2.x;
            acc[2] += w4.z*t2.x; acc[3] += w4.w*t2.x;
            acc[4] += w4.x*t2.y; acc[5] += w4.y*t2.y;
            acc[6] += w4.z*t2.y; acc[7] += w4.w*t2.y;
        }
    }

    int i0 = it*64 + ig*4;
    float ba0 = ld(ba, i0+0, f32), ba1 = ld(ba, i0+1, f32);
    float ba2 = ld(ba, i0+2, f32), ba3 = ld(ba, i0+3, f32);
#pragma unroll
    for (int jt = 0; jt < 2; ++jt) {
        int token = tok0 + tg*2 + jt;
        int n = n0 + tg*2 + jt;
        float4 v;
        v.x = acc[jt*4+0] + ba0 + ld(x1, ((size_t)b*CIN + i0+0)*NT + n, f32);
        v.y = acc[jt*4+1] + ba1 + ld(x1, ((size_t)b*CIN + i0+1)*NT + n, f32);
        v.z = acc[jt*4+2] + ba2 + ld(x1, ((size_t)b*CIN + i0+2)*NT + n, f32);
        v.w = acc[jt*4+3] + ba3 + ld(x1, ((size_t)b*CIN + i0+3)*NT + n, f32);
        *(float4*)&Ap[(size_t)token*CIN + i0] = v;
    }
}

// ---------------- K4: LayerNorm + Linear + ReLU -> out -------------------------
// (r3-measured: 256 blocks, 8 tokens/block)
__global__ void k_ln_out(
    const float* __restrict__ Ap, const u16* __restrict__ ln_g,
    const u16* __restrict__ ln_b, const u16* __restrict__ Wl,
    const u16* __restrict__ bl, u16* __restrict__ out,
    const int* __restrict__ flag)
{
    const int f32 = *flag;
    int tok0 = blockIdx.x * 8;
    int b  = tok0 >> 8;
    int n0 = tok0 & 255;

    __shared__ float At[8][260];

    int t = threadIdx.x;
#pragma unroll
    for (int k = 0; k < 8; ++k)
        At[k][t] = Ap[((size_t)tok0 + k)*CIN + t];
    __syncthreads();

    {   // LN: 32 lanes per token, 8 i-values each
        int kk = t >> 5, lme = t & 31;
        float s = 0.f, s2 = 0.f;
#pragma unroll
        for (int ii = 0; ii < 8; ++ii) { float v = At[kk][lme + 32*ii]; s += v; s2 += v*v; }
#pragma unroll
        for (int off = 1; off < 32; off <<= 1) { s += __shfl_xor(s, off); s2 += __shfl_xor(s2, off); }
        float mu   = s  * (1.f/256.f);
        float var  = s2 * (1.f/256.f) - mu*mu;
        float rstd = rsqrtf(var + 1e-5f);
#pragma unroll
        for (int ii = 0; ii < 8; ++ii) {
            int i = lme + 32*ii;
            float v = At[kk][i];
            At[kk][i] = (v - mu) * rstd * ld(ln_g, i, f32) + ld(ln_b, i, f32);
        }
    }
    __syncthreads();

    int j = t;
    float acc[8];
#pragma unroll
    for (int k = 0; k < 8; ++k) acc[k] = 0.f;

    if (f32) {
        const float* wrow = (const float*)Wl + (size_t)j*CIN;
#pragma unroll 2
        for (int i4 = 0; i4 < 64; ++i4) {
            float4 w4 = *(const float4*)&wrow[4*i4];
#pragma unroll
            for (int k = 0; k < 8; ++k) {
                float4 a = *(const float4*)&At[k][4*i4];
                acc[k] += w4.x*a.x + w4.y*a.y + w4.z*a.z + w4.w*a.w;
            }
        }
    } else {
        const u32* wrow = (const u32*)(Wl + (size_t)j*CIN);
#pragma unroll 2
        for (int i4 = 0; i4 < 64; ++i4) {
            u32 w01 = wrow[2*i4+0], w23 = wrow[2*i4+1];
            float c0 = bf2f((u16)(w01 & 0xFFFFu)), c1 = bf2f((u16)(w01 >> 16));
            float c2 = bf2f((u16)(w23 & 0xFFFFu)), c3 = bf2f((u16)(w23 >> 16));
#pragma unroll
            for (int k = 0; k < 8; ++k) {
                float4 a = *(const float4*)&At[k][4*i4];
                acc[k] += c0*a.x + c1*a.y + c2*a.z + c3*a.w;
            }
        }
    }

    float blv = ld(bl, j, f32);
    size_t obase = ((size_t)b*CIN + j)*NT + n0;
    if (f32) {
        float* o32 = (float*)out;
#pragma unroll
        for (int k = 0; k < 8; ++k)
            o32[obase + k] = fmaxf(acc[k] + blv, 0.f);
    } else {
        u32 pk[4];
#pragma unroll
        for (int k = 0; k < 4; ++k) {
            float f0 = fmaxf(acc[2*k+0] + blv, 0.f);
            float f1 = fmaxf(acc[2*k+1] + blv, 0.f);
            pk[k] = (u32)f2bf(f0) | ((u32)f2bf(f1) << 16);
        }
        U32x4 a0; a0.x = pk[0]; a0.y = pk[1]; a0.z = pk[2]; a0.w = pk[3];
        *(U32x4*)(out + obase) = a0;
    }
}

// ---------------------------------------------------------------
extern "C" void kernel_launch(void* const* d_in, const int* in_sizes, int n_in,
                              void* d_out, int out_size, void* d_ws, size_t ws_size,
                              hipStream_t stream)
{
    const u16* x1   = (const u16*)d_in[0];
    const u16* x2   = (const u16*)d_in[1];
    const u16* Wq   = (const u16*)d_in[2];
    const u16* bq   = (const u16*)d_in[3];
    const u16* Wk   = (const u16*)d_in[4];
    const u16* bk   = (const u16*)d_in[5];
    const u16* Wv   = (const u16*)d_in[6];
    const u16* bv   = (const u16*)d_in[7];
    const u16* Wa   = (const u16*)d_in[8];
    const u16* ba   = (const u16*)d_in[9];
    const u16* ln_g = (const u16*)d_in[10];
    const u16* ln_b = (const u16*)d_in[11];
    const u16* Wl   = (const u16*)d_in[12];
    const u16* bl   = (const u16*)d_in[13];
    u16* out = (u16*)d_out;

    int* flag = (int*)d_ws;
    u16* Qg = (u16*)d_ws + 32;                       // +64 B
    u16* Kg = Qg + (size_t)BB*EMB*NT;                // 1M u16 each
    u16* Vg = Kg + (size_t)BB*EMB*NT;
    float* Oph = (float*)(Vg + (size_t)BB*EMB*NT);   // 2 slabs of 4 MB
    float* Ap  = Oph + 2*(size_t)BB*EMB*NT;
    u16* XTh = (u16*)(Ap + (size_t)BB*NT*CIN);       // 2*8*256*256 u16
    u16* XTl = XTh + (size_t)2*BB*NT*CIN;
    u16* WCh = XTl + (size_t)2*BB*NT*CIN;            // 3*512*256 u16
    u16* WCl = WCh + (size_t)3*EMB*CIN;

    k_xpose   <<<268, 256, 0, stream>>>(x1, x2, Wq, Wk, Wv, XTh, XTl, WCh, WCl, flag);
    k_qkv     <<<768, 256, 0, stream>>>(XTh, XTl, WCh, WCl, bq, bk, bv, Qg, Kg, Vg, flag);
    k_attn    <<<512, 256, 0, stream>>>(Qg, Kg, Vg, Oph);
    k_proj_res<<<256, 256, 0, stream>>>(Oph, Wa, ba, x1, Ap, flag);
    k_ln_out  <<<256, 256, 0, stream>>>(Ap, ln_g, ln_b, Wl, bl, out, flag);
}